// Round 1
// 103.060 us; speedup vs baseline: 1.0094x; 1.0094x over previous
//
#include <hip/hip_runtime.h>
#include <cmath>

// Problem constants
constexpr int Bb  = 2;
constexpr int Nn  = 2048;
constexpr int Dd  = 1024;
constexpr int Hh  = 16;
constexpr int HDd = 64;

// 0.125 (softmax scale) * log2(e), folded into Q at the QKV epilogue
#define QSCALE 0.18033688011112042f

typedef __attribute__((ext_vector_type(8))) _Float16 f16x8;
typedef __attribute__((ext_vector_type(2))) __fp16   fp16x2;
typedef __attribute__((ext_vector_type(4))) float    f32x4;

__device__ inline unsigned short f2h(float f) {    // f32 -> f16 RTN
  _Float16 h = (_Float16)f;
  union { _Float16 h; unsigned short u; } v; v.h = h; return v.u;
}
__device__ inline unsigned cvt_pk_f16(float x, float y) {  // 2xf32 -> packed f16 (RTZ)
  union { fp16x2 h; unsigned u; } v;
  v.h = __builtin_amdgcn_cvt_pkrtz(x, y);
  return v.u;
}
// Single-instruction exp2
__device__ inline float fexp2(float x) {
  float r;
  asm("v_exp_f32 %0, %1" : "=v"(r) : "v"(x));
  return r;
}
__device__ inline void gload16(const void* g, void* l) {
  __builtin_amdgcn_global_load_lds((const __attribute__((address_space(1))) void*)g,
                                   (__attribute__((address_space(3))) void*)l, 16, 0, 0);
}

// ---------------------------------------------------------------------------
// Fused prep: blocks [0,2048) xcast; [2048,2816) w_qkv T+cast; [2816,3072) w_proj
// ---------------------------------------------------------------------------
__global__ __launch_bounds__(256) void prep(
    const float* __restrict__ X, const float* __restrict__ Wq,
    const float* __restrict__ Wp,
    unsigned short* __restrict__ Xf, unsigned short* __restrict__ Bqt,
    unsigned short* __restrict__ Bpt)
{
  const int bid = blockIdx.x;
  const int t = threadIdx.x;

  if (bid < 2048) {   // ---- xcast: 8 f32 -> f16 per thread
    const size_t i = ((size_t)bid * 256 + t) * 8;
    float4 u0 = *(const float4*)(X + i);
    float4 u1 = *(const float4*)(X + i + 4);
    ushort4 a, b;
    a.x = f2h(u0.x); a.y = f2h(u0.y); a.z = f2h(u0.z); a.w = f2h(u0.w);
    b.x = f2h(u1.x); b.y = f2h(u1.y); b.z = f2h(u1.z); b.w = f2h(u1.w);
    *(ushort4*)(Xf + i)     = a;
    *(ushort4*)(Xf + i + 4) = b;
    return;
  }

  __shared__ float T[64][65];
  const float* W; unsigned short* Wt; int Nd, n0, k0;
  if (bid < 2816) {
    const int b2 = bid - 2048;          // 768 blocks: 48 x 16
    W = Wq; Wt = Bqt; Nd = 3 * Dd;
    n0 = (b2 % 48) * 64; k0 = (b2 / 48) * 64;
  } else {
    const int b3 = bid - 2816;          // 256 blocks: 16 x 16
    W = Wp; Wt = Bpt; Nd = Dd;
    n0 = (b3 & 15) * 64; k0 = (b3 >> 4) * 64;
  }
  const int Kd = Dd;
#pragma unroll
  for (int i = 0; i < 4; ++i) {
    int idx = t + 256 * i;
    int r = idx >> 4, c4 = (idx & 15) * 4;
    float4 v = *(const float4*)(W + (size_t)(k0 + r) * Nd + n0 + c4);
    T[c4 + 0][r] = v.x; T[c4 + 1][r] = v.y;
    T[c4 + 2][r] = v.z; T[c4 + 3][r] = v.w;
  }
  __syncthreads();
#pragma unroll
  for (int i = 0; i < 4; ++i) {
    int idx = t + 256 * i;
    int nr = idx >> 4, kc = (idx & 15) * 4;
    ushort4 hv;
    hv.x = f2h(T[nr][kc + 0]); hv.y = f2h(T[nr][kc + 1]);
    hv.z = f2h(T[nr][kc + 2]); hv.w = f2h(T[nr][kc + 3]);
    *(ushort4*)(Wt + (size_t)(n0 + nr) * Kd + k0 + kc) = hv;
  }
}

// ---------------------------------------------------------------------------
// Single-f16 MFMA GEMM (R12 core): 128x128 tile, BK=64,
// single-buffer 32KB LDS (8-chunk swizzle), 4 waves, (256,4).
// EPI 0: fp32 out Cout.  EPI 1: per-head f16 Qf/Kf (QSCALE on Q) + Vtf.
// R19 change: Vtf is written with the sigma kv-permutation
//   sigma(kv) = (kv&~31) | ((kv&12)<<1) | ((kv&16)>>2) | (kv&3)
// so the attention PV B-fragment matches the QK^T C-layout consumed
// directly as the A-fragment (P never staged through LDS).
// ---------------------------------------------------------------------------
template<int EPI>
__global__ __launch_bounds__(256, 4) void gemm_f16(
    const unsigned short* __restrict__ Ag,
    const unsigned short* __restrict__ Bg,
    const float* __restrict__ bias,
    float* __restrict__ Cout,
    unsigned short* __restrict__ Qf, unsigned short* __restrict__ Kf,
    unsigned short* __restrict__ Vtf,
    int Nsz, int Ksz, int gridM)
{
  __shared__ __align__(16) unsigned short A_s[8192];  // 128 rows x 64 k (f16)
  __shared__ __align__(16) unsigned short B_s[8192];

  const int t    = threadIdx.x;
  const int lane = t & 63, w = t >> 6;
  const int g = lane >> 4, lid = lane & 15;
  const int wr = w >> 1, wc = w & 1;

  const int nwg = gridDim.x;
  const int per = nwg >> 3;
  const int bid = (blockIdx.x & 7) * per + (blockIdx.x >> 3);
  const int by = bid % gridM, bx = bid / gridM;
  const int row0 = by * 128, col0 = bx * 128;

  f32x4 acc[4][4];
#pragma unroll
  for (int i = 0; i < 4; ++i)
#pragma unroll
    for (int j = 0; j < 4; ++j) acc[i][j] = f32x4{0.f, 0.f, 0.f, 0.f};

  const int sg8 = ((lane & 7) ^ (lane >> 3)) * 8;  // pre-swizzled src chunk
  const int rl8 = lane >> 3;                        // row within octet

  for (int k0 = 0; k0 < Ksz; k0 += 64) {
#pragma unroll
    for (int q = 0; q < 4; ++q) {
      const int oct = w * 4 + q;        // 0..15
      const int r = oct * 8 + rl8;      // 0..127
      gload16(Ag + (size_t)(row0 + r) * Ksz + k0 + sg8, A_s + oct * 512);
      gload16(Bg + (size_t)(col0 + r) * Ksz + k0 + sg8, B_s + oct * 512);
    }
    __syncthreads();

#pragma unroll
    for (int kk = 0; kk < 2; ++kk) {
      f16x8 a[4], b[4];
#pragma unroll
      for (int mb = 0; mb < 4; ++mb) {
        const int r = wr * 64 + mb * 16 + lid;
        const int off = r * 64 + (((kk * 4 + g) ^ (r & 7)) << 3);
        a[mb] = *(const f16x8*)(A_s + off);
      }
#pragma unroll
      for (int nb = 0; nb < 4; ++nb) {
        const int c = wc * 64 + nb * 16 + lid;
        const int off = c * 64 + (((kk * 4 + g) ^ (c & 7)) << 3);
        b[nb] = *(const f16x8*)(B_s + off);
      }
#pragma unroll
      for (int mb = 0; mb < 4; ++mb)
#pragma unroll
        for (int nb = 0; nb < 4; ++nb)
          acc[mb][nb] = __builtin_amdgcn_mfma_f32_16x16x32_f16(a[mb], b[nb], acc[mb][nb], 0, 0, 0);
    }
    __syncthreads();
  }

#pragma unroll
  for (int nb = 0; nb < 4; ++nb) {
    const int cg = col0 + wc * 64 + nb * 16 + lid;
    const float bv = bias[cg];
    if (EPI == 0) {
#pragma unroll
      for (int mb = 0; mb < 4; ++mb)
#pragma unroll
        for (int reg = 0; reg < 4; ++reg) {
          int nrow = row0 + wr * 64 + mb * 16 + 4 * g + reg;
          Cout[(size_t)nrow * Nsz + cg] = acc[mb][nb][reg] + bv;
        }
    } else {
      const int region = cg >> 10;          // 0=Q 1=K 2=V
      const int h  = (cg & 1023) >> 6;
      const int hd = cg & 63;
      const int b2 = row0 >> 11;
      const int bh_ = b2 * Hh + h;
      const float sc = (region == 0) ? QSCALE : 1.0f;
#pragma unroll
      for (int mb = 0; mb < 4; ++mb) {
        const int nt0 = (row0 & 2047) + wr * 64 + mb * 16 + 4 * g;
        float cc[4];
#pragma unroll
        for (int reg = 0; reg < 4; ++reg) cc[reg] = (acc[mb][nb][reg] + bv) * sc;
        if (region == 2) {
          // sigma kv-permutation (nt0 is a multiple of 4, so the 4
          // consecutive kv stay contiguous: r-bits pass through)
          const int ns = (nt0 & ~31) | ((nt0 & 12) << 1) | ((nt0 & 16) >> 2);
          ushort4 vv;
          vv.x = f2h(cc[0]); vv.y = f2h(cc[1]);
          vv.z = f2h(cc[2]); vv.w = f2h(cc[3]);
          *(ushort4*)(Vtf + ((size_t)bh_ * HDd + hd) * Nn + ns) = vv;
        } else {
          unsigned short* P = (region == 0) ? Qf : Kf;
#pragma unroll
          for (int reg = 0; reg < 4; ++reg)
            P[((size_t)bh_ * Nn + nt0 + reg) * HDd + hd] = f2h(cc[reg]);
        }
      }
    }
  }
}

// ---------------------------------------------------------------------------
// MFMA flash attention, R19: P never touches LDS.
// QK^T C-layout (lane g holds kv = 64h + 16jb + 4g + reg for q = lid) is
// packed with cvt_pk into the PV A-fragment DIRECTLY; V's kv storage is
// sigma-permuted (at the QKV epilogue) so the B-fragment slot (g,j) holds
// the same kv. Removes 8 ds_reads + 16 ds_writes + 2 sched_barriers per
// wave-tile, and 32KB LDS (96->64KB).
// Dual q-strip per wave (shared K/V LDS reads), 4 waves, Q-tile 128,
// grid 512 (2 blocks/CU), KVBLK=128, dbuf, max-free softmax, ones-MFMA
// denominator, native v_exp_f32. LDS 64 KB.
// ---------------------------------------------------------------------------
__global__ __launch_bounds__(256, 2) void attn_mfma(
    const unsigned short* __restrict__ Qf, const unsigned short* __restrict__ Kf,
    const unsigned short* __restrict__ Vt,
    unsigned short* __restrict__ Of)
{
  __shared__ __align__(16) unsigned short Kf_s[16384];    // 2 x [128 kv][64 k]
  __shared__ __align__(16) unsigned short Vt_s[16384];    // 2 x [64 d][128 kv sigma]

  const int t    = threadIdx.x;
  const int lane = t & 63, w = t >> 6;        // 4 waves
  const int g    = lane >> 4, lid = lane & 15;

  const int hw = blockIdx.x;                  // 512 blocks
  const int bh = (hw & 7) * 4 + ((hw >> 3) & 3);
  const int q0 = (hw >> 5) * 128;             // 16 q-blocks per head
  const int b_ = bh >> 4, h_ = bh & 15;

  const size_t kvbase = (size_t)bh * Nn * HDd;

  // Hoisted Q for both strips (B-frag: col=lid, k=g*8+j)
  const int qrowA = q0 + w * 16 + lid;
  const unsigned short* qpA = Qf + kvbase + (size_t)qrowA * HDd + g * 8;
  f16x8 qa0 = *(const f16x8*)(qpA);
  f16x8 qa1 = *(const f16x8*)(qpA + 32);
  const unsigned short* qpB = qpA + (size_t)64 * HDd;
  f16x8 qb0 = *(const f16x8*)(qpB);
  f16x8 qb1 = *(const f16x8*)(qpB + 32);

  f16x8 vones;
#pragma unroll
  for (int i = 0; i < 8; ++i) vones[i] = (_Float16)1.0f;

  f32x4 oA[4], oB[4];
  f32x4 olA = f32x4{0.f, 0.f, 0.f, 0.f};
  f32x4 olB = f32x4{0.f, 0.f, 0.f, 0.f};
#pragma unroll
  for (int i = 0; i < 4; ++i) { oA[i] = f32x4{0.f,0.f,0.f,0.f}; oB[i] = f32x4{0.f,0.f,0.f,0.f}; }

  const int sg8 = ((lane & 7) ^ (lane >> 3)) * 8;  // K staging src chunk

  auto stage = [&](int buf, int kv0) {
#pragma unroll
    for (int q = 0; q < 8; ++q) {
      const int idx = w * 8 + q;            // 0..31 (wave-uniform branch)
      if (idx < 16) {                       // K: octet of 8 kv-rows
        const int r = idx * 8 + (lane >> 3);
        gload16(Kf + kvbase + (size_t)(kv0 + r) * HDd + sg8,
                Kf_s + buf * 8192 + idx * 512);
      } else {                              // V: quad of 4 d-rows, 16 chunks
        const int qd = idx - 16;
        const int r = qd * 4 + (lane >> 4);
        const int srcc = (lane & 15) ^ (r & 15);
        gload16(Vt + kvbase + (size_t)r * Nn + kv0 + srcc * 8,
                Vt_s + buf * 8192 + qd * 512);
      }
    }
  };

  stage(0, 0);
  int cur = 0;
  const int NT = Nn / 128;

  union PU { unsigned u[4]; f16x8 v; };

  for (int tt = 0; tt < NT; ++tt) {
    __syncthreads();   // buf[cur] staged; prior reads of buf[cur^1] done
    if (tt + 1 < NT) stage(cur ^ 1, (tt + 1) * 128);

    const int kb = cur * 8192;

    // ---- S = K Q^T for both strips; each K frag read once, used twice
    f32x4 sA[8], sB[8];
#pragma unroll
    for (int jbb = 0; jbb < 8; ++jbb) { sA[jbb] = f32x4{0.f,0.f,0.f,0.f}; sB[jbb] = f32x4{0.f,0.f,0.f,0.f}; }
    __builtin_amdgcn_s_setprio(1);
#pragma unroll
    for (int jbb = 0; jbb < 8; ++jbb) {
      const int row = jbb * 16 + lid;
      const int rs = kb + row * 64;
      const int sw = row & 7;
      f16x8 kf0 = *(const f16x8*)&Kf_s[rs + ((g       ^ sw)) * 8];
      f16x8 kf1 = *(const f16x8*)&Kf_s[rs + (((4 + g) ^ sw)) * 8];
      sA[jbb] = __builtin_amdgcn_mfma_f32_16x16x32_f16(kf0, qa0, sA[jbb], 0, 0, 0);
      sA[jbb] = __builtin_amdgcn_mfma_f32_16x16x32_f16(kf1, qa1, sA[jbb], 0, 0, 0);
      sB[jbb] = __builtin_amdgcn_mfma_f32_16x16x32_f16(kf0, qb0, sB[jbb], 0, 0, 0);
      sB[jbb] = __builtin_amdgcn_mfma_f32_16x16x32_f16(kf1, qb1, sB[jbb], 0, 0, 0);
    }
    __builtin_amdgcn_s_setprio(0);

    // ---- per 64-kv half: exp2, pack to A-frags in registers, PV
#pragma unroll
    for (int h = 0; h < 2; ++h) {
#pragma unroll
      for (int jb = 0; jb < 4; ++jb)
#pragma unroll
        for (int reg = 0; reg < 4; ++reg) {
          sA[h * 4 + jb][reg] = fexp2(sA[h * 4 + jb][reg]);
          sB[h * 4 + jb][reg] = fexp2(sB[h * 4 + jb][reg]);
        }

      // A-frag slot (g,j) = kv 64h + 16*(j>>2) + 4g + (j&3): lane-local.
      PU pA0, pA1, pB0, pB1;
#pragma unroll
      for (int jb = 0; jb < 2; ++jb) {
        pA0.u[2 * jb + 0] = cvt_pk_f16(sA[h * 4 + jb][0], sA[h * 4 + jb][1]);
        pA0.u[2 * jb + 1] = cvt_pk_f16(sA[h * 4 + jb][2], sA[h * 4 + jb][3]);
        pA1.u[2 * jb + 0] = cvt_pk_f16(sA[h * 4 + 2 + jb][0], sA[h * 4 + 2 + jb][1]);
        pA1.u[2 * jb + 1] = cvt_pk_f16(sA[h * 4 + 2 + jb][2], sA[h * 4 + 2 + jb][3]);
        pB0.u[2 * jb + 0] = cvt_pk_f16(sB[h * 4 + jb][0], sB[h * 4 + jb][1]);
        pB0.u[2 * jb + 1] = cvt_pk_f16(sB[h * 4 + jb][2], sB[h * 4 + jb][3]);
        pB1.u[2 * jb + 0] = cvt_pk_f16(sB[h * 4 + 2 + jb][0], sB[h * 4 + 2 + jb][1]);
        pB1.u[2 * jb + 1] = cvt_pk_f16(sB[h * 4 + 2 + jb][2], sB[h * 4 + 2 + jb][3]);
      }

      __builtin_amdgcn_s_setprio(1);
      olA = __builtin_amdgcn_mfma_f32_16x16x32_f16(pA0.v, vones, olA, 0, 0, 0);
      olA = __builtin_amdgcn_mfma_f32_16x16x32_f16(pA1.v, vones, olA, 0, 0, 0);
      olB = __builtin_amdgcn_mfma_f32_16x16x32_f16(pB0.v, vones, olB, 0, 0, 0);
      olB = __builtin_amdgcn_mfma_f32_16x16x32_f16(pB1.v, vones, olB, 0, 0, 0);
#pragma unroll
      for (int cb = 0; cb < 4; ++cb) {
        const int vrow = cb * 16 + lid;
        const int vs = kb + vrow * 128;
        const int sw = vrow & 15;
        f16x8 vb0 = *(const f16x8*)&Vt_s[vs + (((8 * h + g)     ^ sw)) * 8];
        f16x8 vb1 = *(const f16x8*)&Vt_s[vs + (((8 * h + 4 + g) ^ sw)) * 8];
        oA[cb] = __builtin_amdgcn_mfma_f32_16x16x32_f16(pA0.v, vb0, oA[cb], 0, 0, 0);
        oA[cb] = __builtin_amdgcn_mfma_f32_16x16x32_f16(pA1.v, vb1, oA[cb], 0, 0, 0);
        oB[cb] = __builtin_amdgcn_mfma_f32_16x16x32_f16(pB0.v, vb0, oB[cb], 0, 0, 0);
        oB[cb] = __builtin_amdgcn_mfma_f32_16x16x32_f16(pB1.v, vb1, oB[cb], 0, 0, 0);
      }
      __builtin_amdgcn_s_setprio(0);
    }
    cur ^= 1;
  }

  // ---- epilogue: normalize both strips (l in row layout from ones-MFMA)
  const size_t obaseA = ((size_t)(b_ * Nn + q0 + w * 16)) * Dd + h_ * 64;
  const size_t obaseB = obaseA + (size_t)64 * Dd;
#pragma unroll
  for (int reg = 0; reg < 4; ++reg) {
    const int row = 4 * g + reg;
    const float ivA = 1.0f / olA[reg];
    const float ivB = 1.0f / olB[reg];
#pragma unroll
    for (int cb = 0; cb < 4; ++cb) {
      Of[obaseA + (size_t)row * Dd + cb * 16 + lid] = f2h(oA[cb][reg] * ivA);
      Of[obaseB + (size_t)row * Dd + cb * 16 + lid] = f2h(oB[cb][reg] * ivB);
    }
  }
}

// ---------------------------------------------------------------------------
extern "C" void kernel_launch(void* const* d_in, const int* in_sizes, int n_in,
                              void* d_out, int out_size, void* d_ws, size_t ws_size,
                              hipStream_t stream)
{
  const float* x      = (const float*)d_in[0];
  const float* w_qkv  = (const float*)d_in[1];
  const float* b_qkv  = (const float*)d_in[2];
  const float* w_proj = (const float*)d_in[3];
  const float* b_proj = (const float*)d_in[4];
  float* outp = (float*)d_out;

  unsigned char* ws = (unsigned char*)d_ws;
  const size_t MB = 1ull << 20;
  unsigned short* Xf  = (unsigned short*)(ws +  0 * MB);  // 8 MB f16
  unsigned short* Bqt = (unsigned short*)(ws +  8 * MB);  // 6 MB f16 [3072][1024]
  unsigned short* Qf  = (unsigned short*)(ws + 14 * MB);  // 8 MB
  unsigned short* Kf  = (unsigned short*)(ws + 22 * MB);  // 8 MB
  unsigned short* Vtf = (unsigned short*)(ws + 30 * MB);  // 8 MB (sigma-permuted kv)
  unsigned short* Ofb = (unsigned short*)(ws + 38 * MB);  // 8 MB
  unsigned short* Bpt = (unsigned short*)(ws + 46 * MB);  // 2 MB [1024][1024]

  const int M = Bb * Nn;  // 4096

  // 1) fused prep: x->f16, w_qkv/w_proj -> transposed f16
  prep<<<dim3(3072), 256, 0, stream>>>(x, w_qkv, w_proj, Xf, Bqt, Bpt);

  // 2) QKV GEMM (single f16) -> per-head Qf/Kf/Vtf
  gemm_f16<1><<<dim3((3 * Dd / 128) * (M / 128)), 256, 0, stream>>>(
      Xf, Bqt, b_qkv, nullptr, Qf, Kf, Vtf, 3 * Dd, Dd, M / 128);

  // 3) flash attention -> Of (f16); 512 blocks x 256 threads, Q-tile 128
  attn_mfma<<<dim3((Nn / 128) * Bb * Hh), 256, 0, stream>>>(Qf, Kf, Vtf, Ofb);

  // 4) proj GEMM (single f16) -> fp32 out
  gemm_f16<0><<<dim3((Dd / 128) * (M / 128)), 256, 0, stream>>>(
      Ofb, Bpt, b_proj, outp, nullptr, nullptr, nullptr, Dd, Dd, M / 128);
}

// Round 3
// 100.216 us; speedup vs baseline: 1.0380x; 1.0284x over previous
//
#include <hip/hip_runtime.h>
#include <cmath>

// Problem constants
constexpr int Bb  = 2;
constexpr int Nn  = 2048;
constexpr int Dd  = 1024;
constexpr int Hh  = 16;
constexpr int HDd = 64;

// 0.125 (softmax scale) * log2(e), folded into Q at the QKV epilogue
#define QSCALE 0.18033688011112042f

typedef __attribute__((ext_vector_type(8))) _Float16 f16x8;
typedef __attribute__((ext_vector_type(2))) __fp16   fp16x2;
typedef __attribute__((ext_vector_type(4))) float    f32x4;

__device__ inline unsigned short f2h(float f) {    // f32 -> f16 RTN
  _Float16 h = (_Float16)f;
  union { _Float16 h; unsigned short u; } v; v.h = h; return v.u;
}
__device__ inline unsigned cvt_pk_f16(float x, float y) {  // 2xf32 -> packed f16 (RTZ)
  union { fp16x2 h; unsigned u; } v;
  v.h = __builtin_amdgcn_cvt_pkrtz(x, y);
  return v.u;
}
// Single-instruction exp2
__device__ inline float fexp2(float x) {
  float r;
  asm("v_exp_f32 %0, %1" : "=v"(r) : "v"(x));
  return r;
}
__device__ inline void gload16(const void* g, void* l) {
  __builtin_amdgcn_global_load_lds((const __attribute__((address_space(1))) void*)g,
                                   (__attribute__((address_space(3))) void*)l, 16, 0, 0);
}

// ---------------------------------------------------------------------------
// Fused prep: blocks [0,2048) xcast; [2048,2816) w_qkv T+cast; [2816,3072) w_proj
// ---------------------------------------------------------------------------
__global__ __launch_bounds__(256) void prep(
    const float* __restrict__ X, const float* __restrict__ Wq,
    const float* __restrict__ Wp,
    unsigned short* __restrict__ Xf, unsigned short* __restrict__ Bqt,
    unsigned short* __restrict__ Bpt)
{
  const int bid = blockIdx.x;
  const int t = threadIdx.x;

  if (bid < 2048) {   // ---- xcast: 8 f32 -> f16 per thread
    const size_t i = ((size_t)bid * 256 + t) * 8;
    float4 u0 = *(const float4*)(X + i);
    float4 u1 = *(const float4*)(X + i + 4);
    ushort4 a, b;
    a.x = f2h(u0.x); a.y = f2h(u0.y); a.z = f2h(u0.z); a.w = f2h(u0.w);
    b.x = f2h(u1.x); b.y = f2h(u1.y); b.z = f2h(u1.z); b.w = f2h(u1.w);
    *(ushort4*)(Xf + i)     = a;
    *(ushort4*)(Xf + i + 4) = b;
    return;
  }

  __shared__ float T[64][65];
  const float* W; unsigned short* Wt; int Nd, n0, k0;
  if (bid < 2816) {
    const int b2 = bid - 2048;          // 768 blocks: 48 x 16
    W = Wq; Wt = Bqt; Nd = 3 * Dd;
    n0 = (b2 % 48) * 64; k0 = (b2 / 48) * 64;
  } else {
    const int b3 = bid - 2816;          // 256 blocks: 16 x 16
    W = Wp; Wt = Bpt; Nd = Dd;
    n0 = (b3 & 15) * 64; k0 = (b3 >> 4) * 64;
  }
  const int Kd = Dd;
#pragma unroll
  for (int i = 0; i < 4; ++i) {
    int idx = t + 256 * i;
    int r = idx >> 4, c4 = (idx & 15) * 4;
    float4 v = *(const float4*)(W + (size_t)(k0 + r) * Nd + n0 + c4);
    T[c4 + 0][r] = v.x; T[c4 + 1][r] = v.y;
    T[c4 + 2][r] = v.z; T[c4 + 3][r] = v.w;
  }
  __syncthreads();
#pragma unroll
  for (int i = 0; i < 4; ++i) {
    int idx = t + 256 * i;
    int nr = idx >> 4, kc = (idx & 15) * 4;
    ushort4 hv;
    hv.x = f2h(T[nr][kc + 0]); hv.y = f2h(T[nr][kc + 1]);
    hv.z = f2h(T[nr][kc + 2]); hv.w = f2h(T[nr][kc + 3]);
    *(ushort4*)(Wt + (size_t)(n0 + nr) * Kd + k0 + kc) = hv;
  }
}

// ---------------------------------------------------------------------------
// Single-f16 MFMA GEMM (R12 core), templated on tile-M:
//   BM=128: 128x128 tile, 4 waves as 2x2 (proven R12 config).
//   BM=64 :  64x128 tile, 4 waves as 1x4 col-groups -> 2x the blocks
//            (fixes 1-block/CU occupancy starvation of the proj GEMM).
// BK=64, single-buffer LDS (8-chunk swizzle), (256,4).
// EPI 0: fp32 out Cout.  EPI 1 (BM=128 only): per-head f16 Qf/Kf
// (QSCALE on Q) + sigma-permuted Vtf.
// ---------------------------------------------------------------------------
template<int EPI, int BM>
__global__ __launch_bounds__(256, 4) void gemm_f16(
    const unsigned short* __restrict__ Ag,
    const unsigned short* __restrict__ Bg,
    const float* __restrict__ bias,
    float* __restrict__ Cout,
    unsigned short* __restrict__ Qf, unsigned short* __restrict__ Kf,
    unsigned short* __restrict__ Vtf,
    int Nsz, int Ksz, int gridM)
{
  __shared__ __align__(16) unsigned short A_s[BM * 64];  // BM rows x 64 k (f16)
  __shared__ __align__(16) unsigned short B_s[8192];     // 128 cols x 64 k

  constexpr int NB = 4;                    // col sub-blocks per wave... per layout below
  constexpr int NBW = (BM == 128) ? 4 : 2; // b-frags per wave
  (void)NB;

  const int t    = threadIdx.x;
  const int lane = t & 63, w = t >> 6;
  const int g = lane >> 4, lid = lane & 15;
  const int wr = (BM == 128) ? (w >> 1) : 0;
  const int wcol0 = (BM == 128) ? ((w & 1) * 64) : (w * 32);

  const int nwg = gridDim.x;
  const int per = nwg >> 3;
  const int bid = (blockIdx.x & 7) * per + (blockIdx.x >> 3);
  const int by = bid % gridM, bx = bid / gridM;
  const int row0 = by * BM, col0 = bx * 128;

  f32x4 acc[4][NBW];
#pragma unroll
  for (int i = 0; i < 4; ++i)
#pragma unroll
    for (int j = 0; j < NBW; ++j) acc[i][j] = f32x4{0.f, 0.f, 0.f, 0.f};

  const int sg8 = ((lane & 7) ^ (lane >> 3)) * 8;  // pre-swizzled src chunk
  const int rl8 = lane >> 3;                        // row within octet

  for (int k0 = 0; k0 < Ksz; k0 += 64) {
    if (BM == 128) {
#pragma unroll
      for (int q = 0; q < 4; ++q) {
        const int oct = w * 4 + q;        // 0..15
        const int r = oct * 8 + rl8;      // 0..127
        gload16(Ag + (size_t)(row0 + r) * Ksz + k0 + sg8, A_s + oct * 512);
        gload16(Bg + (size_t)(col0 + r) * Ksz + k0 + sg8, B_s + oct * 512);
      }
    } else {
#pragma unroll
      for (int q = 0; q < 2; ++q) {       // A: 8 octets (64 rows)
        const int oct = w * 2 + q;
        const int r = oct * 8 + rl8;      // 0..63
        gload16(Ag + (size_t)(row0 + r) * Ksz + k0 + sg8, A_s + oct * 512);
      }
#pragma unroll
      for (int q = 0; q < 4; ++q) {       // B: 16 octets (128 cols)
        const int oct = w * 4 + q;
        const int r = oct * 8 + rl8;
        gload16(Bg + (size_t)(col0 + r) * Ksz + k0 + sg8, B_s + oct * 512);
      }
    }
    __syncthreads();

#pragma unroll
    for (int kk = 0; kk < 2; ++kk) {
      f16x8 a[4], b[NBW];
#pragma unroll
      for (int mb = 0; mb < 4; ++mb) {
        const int r = wr * 64 + mb * 16 + lid;
        const int off = r * 64 + (((kk * 4 + g) ^ (r & 7)) << 3);
        a[mb] = *(const f16x8*)(A_s + off);
      }
#pragma unroll
      for (int nb = 0; nb < NBW; ++nb) {
        const int c = wcol0 + nb * 16 + lid;
        const int off = c * 64 + (((kk * 4 + g) ^ (c & 7)) << 3);
        b[nb] = *(const f16x8*)(B_s + off);
      }
#pragma unroll
      for (int mb = 0; mb < 4; ++mb)
#pragma unroll
        for (int nb = 0; nb < NBW; ++nb)
          acc[mb][nb] = __builtin_amdgcn_mfma_f32_16x16x32_f16(a[mb], b[nb], acc[mb][nb], 0, 0, 0);
    }
    __syncthreads();
  }

#pragma unroll
  for (int nb = 0; nb < NBW; ++nb) {
    const int cg = col0 + wcol0 + nb * 16 + lid;
    const float bv = bias[cg];
    if (EPI == 0) {
#pragma unroll
      for (int mb = 0; mb < 4; ++mb)
#pragma unroll
        for (int reg = 0; reg < 4; ++reg) {
          int nrow = row0 + wr * 64 + mb * 16 + 4 * g + reg;
          Cout[(size_t)nrow * Nsz + cg] = acc[mb][nb][reg] + bv;
        }
    } else {
      const int region = cg >> 10;          // 0=Q 1=K 2=V
      const int h  = (cg & 1023) >> 6;
      const int hd = cg & 63;
      const int b2 = row0 >> 11;
      const int bh_ = b2 * Hh + h;
      const float sc = (region == 0) ? QSCALE : 1.0f;
#pragma unroll
      for (int mb = 0; mb < 4; ++mb) {
        const int nt0 = (row0 & 2047) + wr * 64 + mb * 16 + 4 * g;
        float cc[4];
#pragma unroll
        for (int reg = 0; reg < 4; ++reg) cc[reg] = (acc[mb][nb][reg] + bv) * sc;
        if (region == 2) {
          // sigma kv-permutation (nt0 is a multiple of 4, so the 4
          // consecutive kv stay contiguous: r-bits pass through)
          const int ns = (nt0 & ~31) | ((nt0 & 12) << 1) | ((nt0 & 16) >> 2);
          ushort4 vv;
          vv.x = f2h(cc[0]); vv.y = f2h(cc[1]);
          vv.z = f2h(cc[2]); vv.w = f2h(cc[3]);
          *(ushort4*)(Vtf + ((size_t)bh_ * HDd + hd) * Nn + ns) = vv;
        } else {
          unsigned short* P = (region == 0) ? Qf : Kf;
#pragma unroll
          for (int reg = 0; reg < 4; ++reg)
            P[((size_t)bh_ * Nn + nt0 + reg) * HDd + hd] = f2h(cc[reg]);
        }
      }
    }
  }
}

// ---------------------------------------------------------------------------
// MFMA flash attention, R19 (verified passing): P never touches LDS.
// QK^T C-layout (lane g holds kv = 64h + 16jb + 4g + reg for q = lid) is
// packed with cvt_pk into the PV A-fragment DIRECTLY; V's kv storage is
// sigma-permuted (at the QKV epilogue) so the B-fragment slot (g,j) holds
// the same kv.
// Dual q-strip per wave (shared K/V LDS reads), 4 waves, Q-tile 128,
// grid 512 (2 blocks/CU), KVBLK=128, dbuf, max-free softmax, ones-MFMA
// denominator, native v_exp_f32. LDS 64 KB.
// ---------------------------------------------------------------------------
__global__ __launch_bounds__(256, 2) void attn_mfma(
    const unsigned short* __restrict__ Qf, const unsigned short* __restrict__ Kf,
    const unsigned short* __restrict__ Vt,
    unsigned short* __restrict__ Of)
{
  __shared__ __align__(16) unsigned short Kf_s[16384];    // 2 x [128 kv][64 k]
  __shared__ __align__(16) unsigned short Vt_s[16384];    // 2 x [64 d][128 kv sigma]

  const int t    = threadIdx.x;
  const int lane = t & 63, w = t >> 6;        // 4 waves
  const int g    = lane >> 4, lid = lane & 15;

  const int hw = blockIdx.x;                  // 512 blocks
  const int bh = (hw & 7) * 4 + ((hw >> 3) & 3);
  const int q0 = (hw >> 5) * 128;             // 16 q-blocks per head
  const int b_ = bh >> 4, h_ = bh & 15;

  const size_t kvbase = (size_t)bh * Nn * HDd;

  // Hoisted Q for both strips (B-frag: col=lid, k=g*8+j)
  const int qrowA = q0 + w * 16 + lid;
  const unsigned short* qpA = Qf + kvbase + (size_t)qrowA * HDd + g * 8;
  f16x8 qa0 = *(const f16x8*)(qpA);
  f16x8 qa1 = *(const f16x8*)(qpA + 32);
  const unsigned short* qpB = qpA + (size_t)64 * HDd;
  f16x8 qb0 = *(const f16x8*)(qpB);
  f16x8 qb1 = *(const f16x8*)(qpB + 32);

  f16x8 vones;
#pragma unroll
  for (int i = 0; i < 8; ++i) vones[i] = (_Float16)1.0f;

  f32x4 oA[4], oB[4];
  f32x4 olA = f32x4{0.f, 0.f, 0.f, 0.f};
  f32x4 olB = f32x4{0.f, 0.f, 0.f, 0.f};
#pragma unroll
  for (int i = 0; i < 4; ++i) { oA[i] = f32x4{0.f,0.f,0.f,0.f}; oB[i] = f32x4{0.f,0.f,0.f,0.f}; }

  const int sg8 = ((lane & 7) ^ (lane >> 3)) * 8;  // K staging src chunk

  auto stage = [&](int buf, int kv0) {
#pragma unroll
    for (int q = 0; q < 8; ++q) {
      const int idx = w * 8 + q;            // 0..31 (wave-uniform branch)
      if (idx < 16) {                       // K: octet of 8 kv-rows
        const int r = idx * 8 + (lane >> 3);
        gload16(Kf + kvbase + (size_t)(kv0 + r) * HDd + sg8,
                Kf_s + buf * 8192 + idx * 512);
      } else {                              // V: quad of 4 d-rows, 16 chunks
        const int qd = idx - 16;
        const int r = qd * 4 + (lane >> 4);
        const int srcc = (lane & 15) ^ (r & 15);
        gload16(Vt + kvbase + (size_t)r * Nn + kv0 + srcc * 8,
                Vt_s + buf * 8192 + qd * 512);
      }
    }
  };

  stage(0, 0);
  int cur = 0;
  const int NT = Nn / 128;

  union PU { unsigned u[4]; f16x8 v; };

  for (int tt = 0; tt < NT; ++tt) {
    __syncthreads();   // buf[cur] staged; prior reads of buf[cur^1] done
    if (tt + 1 < NT) stage(cur ^ 1, (tt + 1) * 128);

    const int kb = cur * 8192;

    // ---- S = K Q^T for both strips; each K frag read once, used twice
    f32x4 sA[8], sB[8];
#pragma unroll
    for (int jbb = 0; jbb < 8; ++jbb) { sA[jbb] = f32x4{0.f,0.f,0.f,0.f}; sB[jbb] = f32x4{0.f,0.f,0.f,0.f}; }
    __builtin_amdgcn_s_setprio(1);
#pragma unroll
    for (int jbb = 0; jbb < 8; ++jbb) {
      const int row = jbb * 16 + lid;
      const int rs = kb + row * 64;
      const int sw = row & 7;
      f16x8 kf0 = *(const f16x8*)&Kf_s[rs + ((g       ^ sw)) * 8];
      f16x8 kf1 = *(const f16x8*)&Kf_s[rs + (((4 + g) ^ sw)) * 8];
      sA[jbb] = __builtin_amdgcn_mfma_f32_16x16x32_f16(kf0, qa0, sA[jbb], 0, 0, 0);
      sA[jbb] = __builtin_amdgcn_mfma_f32_16x16x32_f16(kf1, qa1, sA[jbb], 0, 0, 0);
      sB[jbb] = __builtin_amdgcn_mfma_f32_16x16x32_f16(kf0, qb0, sB[jbb], 0, 0, 0);
      sB[jbb] = __builtin_amdgcn_mfma_f32_16x16x32_f16(kf1, qb1, sB[jbb], 0, 0, 0);
    }
    __builtin_amdgcn_s_setprio(0);

    // ---- per 64-kv half: exp2, pack to A-frags in registers, PV
#pragma unroll
    for (int h = 0; h < 2; ++h) {
#pragma unroll
      for (int jb = 0; jb < 4; ++jb)
#pragma unroll
        for (int reg = 0; reg < 4; ++reg) {
          sA[h * 4 + jb][reg] = fexp2(sA[h * 4 + jb][reg]);
          sB[h * 4 + jb][reg] = fexp2(sB[h * 4 + jb][reg]);
        }

      // A-frag slot (g,j) = kv 64h + 16*(j>>2) + 4g + (j&3): lane-local.
      PU pA0, pA1, pB0, pB1;
#pragma unroll
      for (int jb = 0; jb < 2; ++jb) {
        pA0.u[2 * jb + 0] = cvt_pk_f16(sA[h * 4 + jb][0], sA[h * 4 + jb][1]);
        pA0.u[2 * jb + 1] = cvt_pk_f16(sA[h * 4 + jb][2], sA[h * 4 + jb][3]);
        pA1.u[2 * jb + 0] = cvt_pk_f16(sA[h * 4 + 2 + jb][0], sA[h * 4 + 2 + jb][1]);
        pA1.u[2 * jb + 1] = cvt_pk_f16(sA[h * 4 + 2 + jb][2], sA[h * 4 + 2 + jb][3]);
        pB0.u[2 * jb + 0] = cvt_pk_f16(sB[h * 4 + jb][0], sB[h * 4 + jb][1]);
        pB0.u[2 * jb + 1] = cvt_pk_f16(sB[h * 4 + jb][2], sB[h * 4 + jb][3]);
        pB1.u[2 * jb + 0] = cvt_pk_f16(sB[h * 4 + 2 + jb][0], sB[h * 4 + 2 + jb][1]);
        pB1.u[2 * jb + 1] = cvt_pk_f16(sB[h * 4 + 2 + jb][2], sB[h * 4 + 2 + jb][3]);
      }

      __builtin_amdgcn_s_setprio(1);
      olA = __builtin_amdgcn_mfma_f32_16x16x32_f16(pA0.v, vones, olA, 0, 0, 0);
      olA = __builtin_amdgcn_mfma_f32_16x16x32_f16(pA1.v, vones, olA, 0, 0, 0);
      olB = __builtin_amdgcn_mfma_f32_16x16x32_f16(pB0.v, vones, olB, 0, 0, 0);
      olB = __builtin_amdgcn_mfma_f32_16x16x32_f16(pB1.v, vones, olB, 0, 0, 0);
#pragma unroll
      for (int cb = 0; cb < 4; ++cb) {
        const int vrow = cb * 16 + lid;
        const int vs = kb + vrow * 128;
        const int sw = vrow & 15;
        f16x8 vb0 = *(const f16x8*)&Vt_s[vs + (((8 * h + g)     ^ sw)) * 8];
        f16x8 vb1 = *(const f16x8*)&Vt_s[vs + (((8 * h + 4 + g) ^ sw)) * 8];
        oA[cb] = __builtin_amdgcn_mfma_f32_16x16x32_f16(pA0.v, vb0, oA[cb], 0, 0, 0);
        oA[cb] = __builtin_amdgcn_mfma_f32_16x16x32_f16(pA1.v, vb1, oA[cb], 0, 0, 0);
        oB[cb] = __builtin_amdgcn_mfma_f32_16x16x32_f16(pB0.v, vb0, oB[cb], 0, 0, 0);
        oB[cb] = __builtin_amdgcn_mfma_f32_16x16x32_f16(pB1.v, vb1, oB[cb], 0, 0, 0);
      }
      __builtin_amdgcn_s_setprio(0);
    }
    cur ^= 1;
  }

  // ---- epilogue: normalize both strips (l in row layout from ones-MFMA)
  const size_t obaseA = ((size_t)(b_ * Nn + q0 + w * 16)) * Dd + h_ * 64;
  const size_t obaseB = obaseA + (size_t)64 * Dd;
#pragma unroll
  for (int reg = 0; reg < 4; ++reg) {
    const int row = 4 * g + reg;
    const float ivA = 1.0f / olA[reg];
    const float ivB = 1.0f / olB[reg];
#pragma unroll
    for (int cb = 0; cb < 4; ++cb) {
      Of[obaseA + (size_t)row * Dd + cb * 16 + lid] = f2h(oA[cb][reg] * ivA);
      Of[obaseB + (size_t)row * Dd + cb * 16 + lid] = f2h(oB[cb][reg] * ivB);
    }
  }
}

// ---------------------------------------------------------------------------
extern "C" void kernel_launch(void* const* d_in, const int* in_sizes, int n_in,
                              void* d_out, int out_size, void* d_ws, size_t ws_size,
                              hipStream_t stream)
{
  const float* x      = (const float*)d_in[0];
  const float* w_qkv  = (const float*)d_in[1];
  const float* b_qkv  = (const float*)d_in[2];
  const float* w_proj = (const float*)d_in[3];
  const float* b_proj = (const float*)d_in[4];
  float* outp = (float*)d_out;

  unsigned char* ws = (unsigned char*)d_ws;
  const size_t MB = 1ull << 20;
  unsigned short* Xf  = (unsigned short*)(ws +  0 * MB);  // 8 MB f16
  unsigned short* Bqt = (unsigned short*)(ws +  8 * MB);  // 6 MB f16 [3072][1024]
  unsigned short* Qf  = (unsigned short*)(ws + 14 * MB);  // 8 MB
  unsigned short* Kf  = (unsigned short*)(ws + 22 * MB);  // 8 MB
  unsigned short* Vtf = (unsigned short*)(ws + 30 * MB);  // 8 MB (sigma-permuted kv)
  unsigned short* Ofb = (unsigned short*)(ws + 38 * MB);  // 8 MB
  unsigned short* Bpt = (unsigned short*)(ws + 46 * MB);  // 2 MB [1024][1024]

  const int M = Bb * Nn;  // 4096

  // 1) fused prep: x->f16, w_qkv/w_proj -> transposed f16
  prep<<<dim3(3072), 256, 0, stream>>>(x, w_qkv, w_proj, Xf, Bqt, Bpt);

  // 2) QKV GEMM (128x128 tiles, 768 blocks = 3/CU) -> per-head Qf/Kf/Vtf
  gemm_f16<1, 128><<<dim3((3 * Dd / 128) * (M / 128)), 256, 0, stream>>>(
      Xf, Bqt, b_qkv, nullptr, Qf, Kf, Vtf, 3 * Dd, Dd, M / 128);

  // 3) flash attention -> Of (f16); 512 blocks x 256 threads, Q-tile 128
  attn_mfma<<<dim3((Nn / 128) * Bb * Hh), 256, 0, stream>>>(Qf, Kf, Vtf, Ofb);

  // 4) proj GEMM (64x128 tiles, 512 blocks = 2/CU) -> fp32 out
  gemm_f16<0, 64><<<dim3((Dd / 128) * (M / 64)), 256, 0, stream>>>(
      Ofb, Bpt, b_proj, outp, nullptr, nullptr, nullptr, Dd, Dd, M / 64);
}